// Round 1
// baseline (804.381 us; speedup 1.0000x reference)
//
#include <hip/hip_runtime.h>
#include <hip/hip_bf16.h>
#include <stdint.h>

// Problem constants
#define B_ 1024
#define T_ 64
#define D_ 256
#define H_ 256
#define G_ 1024   // 4*H

typedef float f32x4 __attribute__((ext_vector_type(4)));
typedef __bf16 bf16x8 __attribute__((ext_vector_type(8)));

__device__ __forceinline__ float bf2f(unsigned short u) {
    unsigned int x = ((unsigned int)u) << 16;
    return __builtin_bit_cast(float, x);
}
__device__ __forceinline__ unsigned short f2bf(float f) {
    __hip_bfloat16 h = __float2bfloat16(f);   // RNE
    return __builtin_bit_cast(unsigned short, h);
}

// ---------------------------------------------------------------------------
// prep_w: W_ih, W_hh f32 -> bf16 (row-major, same layout); bias = b_ih + b_hh
// grid 1024 x 256
__global__ void prep_w_kernel(const float* __restrict__ Wih, const float* __restrict__ Whh,
                              const float* __restrict__ bih, const float* __restrict__ bhh,
                              unsigned short* __restrict__ wih_bf, unsigned short* __restrict__ whh_bf,
                              float* __restrict__ bias) {
    int i = blockIdx.x * 256 + threadIdx.x;   // covers G_*D_ exactly
    wih_bf[i] = f2bf(Wih[i]);
    whh_bf[i] = f2bf(Whh[i]);
    if (i < G_) bias[i] = bih[i] + bhh[i];
}

// ---------------------------------------------------------------------------
// prep_attn: x_score[b,d] = sum_t x[b,t,d]*w_x[t];  attn[b,:] = softmax_d(x_score)
// (s_hc and b_attn cancel in the softmax). grid 1024 blocks x 256 threads.
__global__ void prep_attn_kernel(const float* __restrict__ x, const float* __restrict__ Wattn,
                                 float* __restrict__ attn) {
    __shared__ float wx[T_];
    __shared__ float red[256];
    int b = blockIdx.x, d = threadIdx.x;
    if (d < T_) wx[d] = Wattn[2 * H_ + d];
    __syncthreads();
    const float* xb = x + (size_t)b * T_ * D_ + d;
    float s = 0.f;
    #pragma unroll
    for (int t = 0; t < T_; ++t) s += xb[t * D_] * wx[t];
    red[d] = s;
    __syncthreads();
    for (int o = 128; o > 0; o >>= 1) {
        if (d < o) red[d] = fmaxf(red[d], red[d + o]);
        __syncthreads();
    }
    float m = red[0];
    __syncthreads();
    float e = __expf(s - m);
    red[d] = e;
    __syncthreads();
    for (int o = 128; o > 0; o >>= 1) {
        if (d < o) red[d] += red[d + o];
        __syncthreads();
    }
    attn[b * D_ + d] = e * (1.f / red[0]);
}

// ---------------------------------------------------------------------------
// winw: w_in = attn (*) x. Writes f32 output 0 ([b][t][d]) and bf16 copy in
// t-major layout [t][b][d] for the GEMM. grid 16384 x 256, one float4/thread.
__global__ void winw_kernel(const float* __restrict__ x, const float* __restrict__ attn,
                            float* __restrict__ w_out, unsigned short* __restrict__ win_bf) {
    int i4 = blockIdx.x * 256 + threadIdx.x;  // [0, B*T*D/4)
    int e  = i4 * 4;
    int d  = e & 255;
    int bt = e >> 8;            // b*64 + t
    int b  = bt >> 6, t = bt & 63;
    f32x4 xv = *(const f32x4*)(x + e);
    f32x4 av = *(const f32x4*)(attn + b * D_ + d);
    f32x4 w  = xv * av;
    *(f32x4*)(w_out + e) = w;
    ushort4 u;
    u.x = f2bf(w[0]); u.y = f2bf(w[1]); u.z = f2bf(w[2]); u.w = f2bf(w[3]);
    *(ushort4*)(win_bf + ((size_t)(t * B_ + b) * D_ + d)) = u;
}

// ---------------------------------------------------------------------------
// gemmx: pre_gates[m][n] = sum_k w_in[m][k] * W_ih[n][k], m = t*1024+b (65536),
// n in [0,1024), k in [0,256). 128x128 tile, 4 waves (2x2), direct-global
// MFMA fragments (no LDS; B is L2-resident, A is L3-resident).
__global__ __launch_bounds__(256, 2) void gemmx_kernel(const unsigned short* __restrict__ A,
                                                       const unsigned short* __restrict__ Bw,
                                                       unsigned short* __restrict__ pre) {
    int bx = blockIdx.x;               // 4096 = 512 x 8
    int bn = bx & 7, bm = bx >> 3;
    int tid = threadIdx.x, lane = tid & 63, w = tid >> 6;
    int wr = w >> 1, wc = w & 1;
    int m0 = bm * 128 + wr * 64, n0 = bn * 128 + wc * 64;
    int lr = lane & 15, lk = (lane >> 4) * 8;

    const unsigned short* Ab[4];
    const unsigned short* Bb[4];
    #pragma unroll
    for (int i = 0; i < 4; ++i) {
        Ab[i] = A  + (size_t)(m0 + i * 16 + lr) * D_ + lk;
        Bb[i] = Bw + (size_t)(n0 + i * 16 + lr) * D_ + lk;
    }
    f32x4 acc[4][4] = {};
    #pragma unroll
    for (int kk = 0; kk < 8; ++kk) {
        bf16x8 a[4], bb[4];
        #pragma unroll
        for (int i = 0; i < 4; ++i) {
            a[i]  = *(const bf16x8*)(Ab[i] + kk * 32);
            bb[i] = *(const bf16x8*)(Bb[i] + kk * 32);
        }
        #pragma unroll
        for (int mi = 0; mi < 4; ++mi)
            #pragma unroll
            for (int ni = 0; ni < 4; ++ni)
                acc[mi][ni] = __builtin_amdgcn_mfma_f32_16x16x32_bf16(a[mi], bb[ni], acc[mi][ni], 0, 0, 0);
    }
    int orow = (lane >> 4) * 4;
    #pragma unroll
    for (int mi = 0; mi < 4; ++mi)
        #pragma unroll
        for (int ni = 0; ni < 4; ++ni)
            #pragma unroll
            for (int q = 0; q < 4; ++q) {
                int m = m0 + mi * 16 + orow + q;
                int n = n0 + ni * 16 + lr;
                pre[(size_t)m * G_ + n] = f2bf(acc[mi][ni][q]);
            }
}

// ---------------------------------------------------------------------------
// seqs: sequential LSTM. 64 blocks x 512 threads (8 waves), block = 16 batch
// rows, no grid syncs. Per step: gates = h@W_hh^T (MFMA, K=256) + pre_gates +
// bias; cell update in f32; h -> LDS (bf16) for next step's A fragments.
// Wave w owns h-cols j in [w*32, w*32+32): its 8 MFMA N-tiles are the
// matching i/f/g/o columns, so the cell update is fully in-register.
__global__ __launch_bounds__(512, 2) void seqs_kernel(const unsigned short* __restrict__ pre,
                                                      const unsigned short* __restrict__ Whh,
                                                      const float* __restrict__ bias,
                                                      float* __restrict__ enc_out) {
    __shared__ unsigned short h_lds[16 * 264];     // pitch 264 (bank-conflict pad)
    __shared__ unsigned short pre_lds[16 * G_];    // 32 KB staging of pre_gates[t]
    int tid = threadIdx.x, lane = tid & 63, w = tid >> 6;
    int lr = lane & 15, hi = lane >> 4, lk = hi * 8;
    int r0 = blockIdx.x * 16;
    int jbase = w * 32;

    for (int i = tid; i < 16 * 264; i += 512) h_lds[i] = 0;

    float c[2][4] = {};
    float bias_r[2][4];
    const unsigned short* Wb[2][4];
    #pragma unroll
    for (int jt = 0; jt < 2; ++jt)
        #pragma unroll
        for (int g = 0; g < 4; ++g) {
            int n = g * 256 + jbase + jt * 16 + lr;
            bias_r[jt][g] = bias[n];
            Wb[jt][g] = Whh + (size_t)n * H_ + lk;
        }
    __syncthreads();

    for (int t = 0; t < T_; ++t) {
        // issue pre_gates[t] stage loads early (latency hides under MFMA loop)
        uint4 stg[4];
        const uint4* src = (const uint4*)(pre + ((size_t)t * B_ + r0) * G_);
        #pragma unroll
        for (int s = 0; s < 4; ++s) stg[s] = src[tid + s * 512];

        // K-loop: gates_h = h @ W_hh^T
        f32x4 acc[2][4] = {};
        #pragma unroll
        for (int kk = 0; kk < 8; ++kk) {
            bf16x8 a = *(const bf16x8*)&h_lds[lr * 264 + kk * 32 + lk];
            #pragma unroll
            for (int jt = 0; jt < 2; ++jt)
                #pragma unroll
                for (int g = 0; g < 4; ++g) {
                    bf16x8 bfrag = *(const bf16x8*)(Wb[jt][g] + kk * 32);
                    acc[jt][g] = __builtin_amdgcn_mfma_f32_16x16x32_bf16(a, bfrag, acc[jt][g], 0, 0, 0);
                }
        }
        // commit staged pre_gates to LDS
        uint4* pl = (uint4*)pre_lds;
        #pragma unroll
        for (int s = 0; s < 4; ++s) pl[tid + s * 512] = stg[s];
        __syncthreads();   // h_lds reads done + pre_lds visible

        // cell update (f32)
        #pragma unroll
        for (int q = 0; q < 4; ++q) {
            int m = hi * 4 + q;
            #pragma unroll
            for (int jt = 0; jt < 2; ++jt) {
                int j  = jbase + jt * 16 + lr;
                float gi = acc[jt][0][q] + bf2f(pre_lds[m * G_ +       j]) + bias_r[jt][0];
                float gf = acc[jt][1][q] + bf2f(pre_lds[m * G_ + 256 + j]) + bias_r[jt][1];
                float gg = acc[jt][2][q] + bf2f(pre_lds[m * G_ + 512 + j]) + bias_r[jt][2];
                float go = acc[jt][3][q] + bf2f(pre_lds[m * G_ + 768 + j]) + bias_r[jt][3];
                float si = 1.f / (1.f + __expf(-gi));
                float sf = 1.f / (1.f + __expf(-gf));
                float so = 1.f / (1.f + __expf(-go));
                float eg = __expf(2.f * gg);
                float tg = (eg - 1.f) / (eg + 1.f);
                float cn = sf * c[jt][q] + si * tg;
                c[jt][q] = cn;
                float ec = __expf(2.f * cn);
                float tc = (ec - 1.f) / (ec + 1.f);
                float h  = so * tc;
                h_lds[m * 264 + j] = f2bf(h);
                enc_out[((size_t)(r0 + m) * T_ + t) * H_ + j] = h;
            }
        }
        __syncthreads();   // h_lds writes visible before next K-loop
    }
}

// ---------------------------------------------------------------------------
extern "C" void kernel_launch(void* const* d_in, const int* in_sizes, int n_in,
                              void* d_out, int out_size, void* d_ws, size_t ws_size,
                              hipStream_t stream) {
    const float* x     = (const float*)d_in[0];
    const float* Wattn = (const float*)d_in[1];
    // d_in[2] = b_attn (cancels in softmax)
    const float* Wih   = (const float*)d_in[3];
    const float* Whh   = (const float*)d_in[4];
    const float* bih   = (const float*)d_in[5];
    const float* bhh   = (const float*)d_in[6];

    char* ws = (char*)d_ws;
    float*          attn   = (float*)(ws);                            // 1 MB
    unsigned short* win_bf = (unsigned short*)(ws + 1048576);         // 32 MB [t][b][d]
    unsigned short* wih_bf = (unsigned short*)(ws + 34603008);        // 512 KB
    unsigned short* whh_bf = (unsigned short*)(ws + 35127296);        // 512 KB
    float*          bias   = (float*)(ws + 35651584);                 // 4 KB
    unsigned short* pre    = (unsigned short*)(ws + 35655680);        // 128 MB [t][b][n]

    float* w_out   = (float*)d_out;                                   // output 0
    float* enc_out = (float*)d_out + (size_t)B_ * T_ * D_;            // output 1

    prep_w_kernel<<<dim3(1024), dim3(256), 0, stream>>>(Wih, Whh, bih, bhh, wih_bf, whh_bf, bias);
    prep_attn_kernel<<<dim3(1024), dim3(256), 0, stream>>>(x, Wattn, attn);
    winw_kernel<<<dim3(16384), dim3(256), 0, stream>>>(x, attn, w_out, win_bf);
    gemmx_kernel<<<dim3(4096), dim3(256), 0, stream>>>(win_bf, wih_bf, pre);
    seqs_kernel<<<dim3(64), dim3(512), 0, stream>>>(pre, whh_bf, bias, enc_out);
}